// Round 3
// baseline (281.850 us; speedup 1.0000x reference)
//
#include <hip/hip_runtime.h>
#include <math.h>

#define NB   64
#define NL   512
#define ND   768
#define NP   128
#define NHID 1024
#define NTOK (NB * NL)

typedef float f4 __attribute__((ext_vector_type(4)));

// One 64-lane wave per TWO tokens. Per token, lane layout:
//   token path: 12 floats/lane at h = lane*12     (768 total)
//   pos   path:  4 floats/lane at h = 768+lane*4  (256 total)
// Single-pass LN: sum & sumsq reduced in one butterfly; 4 independent
// reduction chains (s0,p0,s1,p1) pipeline through the DS unit.
__global__ __launch_bounds__(256)
void molt_embed_ln(
    const int*   __restrict__ input_ids,
    const int*   __restrict__ token_type_ids,
    const int*   __restrict__ pos_embed_ids,
    const float* __restrict__ lp_embeds,
    const int*   __restrict__ p_ring,
    const int*   __restrict__ p_charge,
    const int*   __restrict__ p_hyb,
    const int*   __restrict__ p_chir,
    const int*   __restrict__ p_arom,
    const int*   __restrict__ p_conj,
    const int*   __restrict__ p_stereo,
    const float* __restrict__ mol_features,
    const float* __restrict__ target_values,
    const float* __restrict__ emb_table,
    const float* __restrict__ type_table,
    const float* __restrict__ ring_tab,
    const float* __restrict__ charge_tab,
    const float* __restrict__ hyb_tab,
    const float* __restrict__ chir_tab,
    const float* __restrict__ arom_tab,
    const float* __restrict__ conj_tab,
    const float* __restrict__ stereo_tab,
    const float* __restrict__ ln_gamma,
    const float* __restrict__ ln_beta,
    float*       __restrict__ out)
{
    const int lane = threadIdx.x & 63;
    int t0 = (blockIdx.x << 3) + ((threadIdx.x >> 6) << 1);
    t0 = __builtin_amdgcn_readfirstlane(t0);   // wave-uniform -> SGPR index loads
    const int t1 = t0 + 1;                     // same batch (pairs never cross x512)
    const int b  = t0 >> 9;
    const int h0 = lane * 12;                  // 48B, 16B-aligned

    f4 v0[4], v1[4];

    auto tok = [&](int t, f4* v) {
        const int id   = input_ids[t];
        const int tt   = token_type_ids[t];
        const int ir   = p_ring[t];
        const int ic   = p_charge[t];
        const int ihy  = p_hyb[t];
        const int ichr = p_chir[t];
        const int ia   = p_arom[t];
        const int icj  = p_conj[t];
        const int ist  = p_stereo[t];

        float scale = 1.0f;
        if (tt == 5)      scale += mol_features[t];   // FEAT
        else if (tt == 6) scale += target_values[t];  // TGT

        const f4* e  = (const f4*)(emb_table  + (size_t)id   * ND + h0);
        const f4* ty = (const f4*)(type_table + (size_t)tt   * ND + h0);
        const f4* r  = (const f4*)(ring_tab   + (size_t)ir   * ND + h0);
        const f4* c  = (const f4*)(charge_tab + (size_t)ic   * ND + h0);
        const f4* hy = (const f4*)(hyb_tab    + (size_t)ihy  * ND + h0);
        const f4* ch = (const f4*)(chir_tab   + (size_t)ichr * ND + h0);
        const f4* ar = (const f4*)(arom_tab   + (size_t)ia   * ND + h0);
        const f4* cj = (const f4*)(conj_tab   + (size_t)icj  * ND + h0);
        const f4* st = (const f4*)(stereo_tab + (size_t)ist  * ND + h0);

        #pragma unroll
        for (int j = 0; j < 3; ++j) {
            f4 s = ty[j] + r[j] + c[j] + hy[j] + ch[j] + ar[j] + cj[j] + st[j];
            v[j] = e[j] * scale + s;
        }

        const int kk  = lane >> 5;             // 0 or 1 (K index)
        const int pp  = (lane & 31) << 2;      // 0..124
        const int pid = pos_embed_ids[(t << 1) + kk];
        f4 a = *(const f4*)(lp_embeds + ((size_t)(b * NL + pid)) * NP + pp);
        #pragma unroll
        for (int k = 0; k < 4; ++k) a[k] = (a[k] == a[k]) ? a[k] : 0.0f;
        v[3] = a;
    };
    tok(t0, v0);
    tok(t1, v1);

    // ---- single-pass sum + sumsq, 4 independent butterfly chains ----
    float s0 = 0.f, p0 = 0.f, s1 = 0.f, p1 = 0.f;
    #pragma unroll
    for (int j = 0; j < 4; ++j) {
        #pragma unroll
        for (int k = 0; k < 4; ++k) {
            float a = v0[j][k], c = v1[j][k];
            s0 += a; p0 += a * a;
            s1 += c; p1 += c * c;
        }
    }
    #pragma unroll
    for (int off = 32; off; off >>= 1) {
        s0 += __shfl_xor(s0, off, 64);
        s1 += __shfl_xor(s1, off, 64);
        p0 += __shfl_xor(p0, off, 64);
        p1 += __shfl_xor(p1, off, 64);
    }
    const float mean0 = s0 * (1.0f / (float)NHID);
    const float mean1 = s1 * (1.0f / (float)NHID);
    const float var0  = fmaxf(p0 * (1.0f / (float)NHID) - mean0 * mean0, 0.0f);
    const float var1  = fmaxf(p1 * (1.0f / (float)NHID) - mean1 * mean1, 0.0f);
    const float inv0  = 1.0f / sqrtf(var0 + 1e-12f);
    const float inv1  = 1.0f / sqrtf(var1 + 1e-12f);

    // ---- write (non-temporal: keep the 134MB stream out of L2) ----
    float* o0 = out + (size_t)t0 * NHID;
    float* o1 = out + (size_t)t1 * NHID;
    #pragma unroll
    for (int j = 0; j < 3; ++j) {
        f4 g  = *(const f4*)(ln_gamma + h0 + 4 * j);
        f4 be = *(const f4*)(ln_beta  + h0 + 4 * j);
        f4 q0 = (v0[j] - mean0) * inv0 * g + be;
        f4 q1 = (v1[j] - mean1) * inv1 * g + be;
        __builtin_nontemporal_store(q0, (f4*)(o0 + h0 + 4 * j));
        __builtin_nontemporal_store(q1, (f4*)(o1 + h0 + 4 * j));
    }
    {
        const int hp = ND + (lane << 2);
        f4 g  = *(const f4*)(ln_gamma + hp);
        f4 be = *(const f4*)(ln_beta  + hp);
        f4 q0 = (v0[3] - mean0) * inv0 * g + be;
        f4 q1 = (v1[3] - mean1) * inv1 * g + be;
        __builtin_nontemporal_store(q0, (f4*)(o0 + hp));
        __builtin_nontemporal_store(q1, (f4*)(o1 + hp));
    }
}

extern "C" void kernel_launch(void* const* d_in, const int* in_sizes, int n_in,
                              void* d_out, int out_size, void* d_ws, size_t ws_size,
                              hipStream_t stream) {
    (void)in_sizes; (void)n_in; (void)out_size; (void)d_ws; (void)ws_size;
    molt_embed_ln<<<NTOK / 8, 256, 0, stream>>>(
        (const int*)d_in[0],  (const int*)d_in[1],  (const int*)d_in[2],
        (const float*)d_in[3],
        (const int*)d_in[4],  (const int*)d_in[5],  (const int*)d_in[6],
        (const int*)d_in[7],  (const int*)d_in[8],  (const int*)d_in[9],
        (const int*)d_in[10],
        (const float*)d_in[11], (const float*)d_in[12],
        (const float*)d_in[13], (const float*)d_in[14], (const float*)d_in[15],
        (const float*)d_in[16], (const float*)d_in[17], (const float*)d_in[18],
        (const float*)d_in[19], (const float*)d_in[20], (const float*)d_in[21],
        (const float*)d_in[22], (const float*)d_in[23],
        (float*)d_out);
}

// Round 4
// 245.616 us; speedup vs baseline: 1.1475x; 1.1475x over previous
//
#include <hip/hip_runtime.h>
#include <math.h>

#define NB   64
#define NL   512
#define ND   768
#define NP   128
#define NHID 1024
#define NTOK (NB * NL)

typedef float f4 __attribute__((ext_vector_type(4)));

// One 64-lane wave per TWO tokens. Chunked-contiguous lane layout:
//   chunk j (j=0..3): elements [j*256 + lane*4, +4)
//   chunks 0-2 = token path (768), chunk 3 = pos path (256)
// Every load/store instruction covers 1KB contiguous per wave -> full
// 64B sectors -> non-temporal stores cannot write-amplify (R2 lesson:
// strided 16B nt stores drained partial sectors, 2.13x WRITE_SIZE).
__global__ __launch_bounds__(256)
void molt_embed_ln(
    const int*   __restrict__ input_ids,
    const int*   __restrict__ token_type_ids,
    const int*   __restrict__ pos_embed_ids,
    const float* __restrict__ lp_embeds,
    const int*   __restrict__ p_ring,
    const int*   __restrict__ p_charge,
    const int*   __restrict__ p_hyb,
    const int*   __restrict__ p_chir,
    const int*   __restrict__ p_arom,
    const int*   __restrict__ p_conj,
    const int*   __restrict__ p_stereo,
    const float* __restrict__ mol_features,
    const float* __restrict__ target_values,
    const float* __restrict__ emb_table,
    const float* __restrict__ type_table,
    const float* __restrict__ ring_tab,
    const float* __restrict__ charge_tab,
    const float* __restrict__ hyb_tab,
    const float* __restrict__ chir_tab,
    const float* __restrict__ arom_tab,
    const float* __restrict__ conj_tab,
    const float* __restrict__ stereo_tab,
    const float* __restrict__ ln_gamma,
    const float* __restrict__ ln_beta,
    float*       __restrict__ out)
{
    const int lane = threadIdx.x & 63;
    int t0 = (blockIdx.x << 3) + ((threadIdx.x >> 6) << 1);
    t0 = __builtin_amdgcn_readfirstlane(t0);   // wave-uniform -> SGPR index loads
    const int t1 = t0 + 1;                     // same batch (pairs never cross x512)
    const int b  = t0 >> 9;
    const int h  = lane << 2;                  // 0..252, 16B-aligned

    f4 v0[4], v1[4];

    auto tok = [&](int t, f4* v) {
        const int id   = input_ids[t];
        const int tt   = token_type_ids[t];
        const int ir   = p_ring[t];
        const int ic   = p_charge[t];
        const int ihy  = p_hyb[t];
        const int ichr = p_chir[t];
        const int ia   = p_arom[t];
        const int icj  = p_conj[t];
        const int ist  = p_stereo[t];

        float scale = 1.0f;
        if (tt == 5)      scale += mol_features[t];   // FEAT
        else if (tt == 6) scale += target_values[t];  // TGT

        const float* e  = emb_table  + (size_t)id   * ND;
        const float* ty = type_table + (size_t)tt   * ND;
        const float* r  = ring_tab   + (size_t)ir   * ND;
        const float* c  = charge_tab + (size_t)ic   * ND;
        const float* hy = hyb_tab    + (size_t)ihy  * ND;
        const float* ch = chir_tab   + (size_t)ichr * ND;
        const float* ar = arom_tab   + (size_t)ia   * ND;
        const float* cj = conj_tab   + (size_t)icj  * ND;
        const float* st = stereo_tab + (size_t)ist  * ND;

        #pragma unroll
        for (int j = 0; j < 3; ++j) {
            const int off = j * 256 + h;       // 1KB contiguous per wave per instr
            f4 s = *(const f4*)(ty + off) + *(const f4*)(r  + off)
                 + *(const f4*)(c  + off) + *(const f4*)(hy + off)
                 + *(const f4*)(ch + off) + *(const f4*)(ar + off)
                 + *(const f4*)(cj + off) + *(const f4*)(st + off);
            v[j] = *(const f4*)(e + off) * scale + s;
        }

        const int kk  = lane >> 5;             // K index (0/1)
        const int pp  = (lane & 31) << 2;      // 0..124
        const int pid = pos_embed_ids[(t << 1) + kk];
        f4 a = *(const f4*)(lp_embeds + ((size_t)(b * NL + pid)) * NP + pp);
        #pragma unroll
        for (int k = 0; k < 4; ++k) a[k] = (a[k] == a[k]) ? a[k] : 0.0f;
        v[3] = a;
    };
    tok(t0, v0);
    tok(t1, v1);

    // ---- single-pass sum + sumsq, 4 independent butterfly chains ----
    float s0 = 0.f, p0 = 0.f, s1 = 0.f, p1 = 0.f;
    #pragma unroll
    for (int j = 0; j < 4; ++j) {
        #pragma unroll
        for (int k = 0; k < 4; ++k) {
            float a = v0[j][k], c = v1[j][k];
            s0 += a; p0 += a * a;
            s1 += c; p1 += c * c;
        }
    }
    #pragma unroll
    for (int off = 32; off; off >>= 1) {
        s0 += __shfl_xor(s0, off, 64);
        s1 += __shfl_xor(s1, off, 64);
        p0 += __shfl_xor(p0, off, 64);
        p1 += __shfl_xor(p1, off, 64);
    }
    const float mean0 = s0 * (1.0f / (float)NHID);
    const float mean1 = s1 * (1.0f / (float)NHID);
    const float var0  = fmaxf(p0 * (1.0f / (float)NHID) - mean0 * mean0, 0.0f);
    const float var1  = fmaxf(p1 * (1.0f / (float)NHID) - mean1 * mean1, 0.0f);
    const float inv0  = 1.0f / sqrtf(var0 + 1e-12f);
    const float inv1  = 1.0f / sqrtf(var1 + 1e-12f);

    // ---- write: 1KB-contiguous nt stores (full sectors, no amplification) ----
    float* o0 = out + (size_t)t0 * NHID;
    float* o1 = out + (size_t)t1 * NHID;
    #pragma unroll
    for (int j = 0; j < 4; ++j) {
        const int off = j * 256 + h;
        f4 g  = *(const f4*)(ln_gamma + off);
        f4 be = *(const f4*)(ln_beta  + off);
        f4 q0 = (v0[j] - mean0) * inv0 * g + be;
        f4 q1 = (v1[j] - mean1) * inv1 * g + be;
        __builtin_nontemporal_store(q0, (f4*)(o0 + off));
        __builtin_nontemporal_store(q1, (f4*)(o1 + off));
    }
}

extern "C" void kernel_launch(void* const* d_in, const int* in_sizes, int n_in,
                              void* d_out, int out_size, void* d_ws, size_t ws_size,
                              hipStream_t stream) {
    (void)in_sizes; (void)n_in; (void)out_size; (void)d_ws; (void)ws_size;
    molt_embed_ln<<<NTOK / 8, 256, 0, stream>>>(
        (const int*)d_in[0],  (const int*)d_in[1],  (const int*)d_in[2],
        (const float*)d_in[3],
        (const int*)d_in[4],  (const int*)d_in[5],  (const int*)d_in[6],
        (const int*)d_in[7],  (const int*)d_in[8],  (const int*)d_in[9],
        (const int*)d_in[10],
        (const float*)d_in[11], (const float*)d_in[12],
        (const float*)d_in[13], (const float*)d_in[14], (const float*)d_in[15],
        (const float*)d_in[16], (const float*)d_in[17], (const float*)d_in[18],
        (const float*)d_in[19], (const float*)d_in[20], (const float*)d_in[21],
        (const float*)d_in[22], (const float*)d_in[23],
        (float*)d_out);
}